// Round 1
// baseline (680.381 us; speedup 1.0000x reference)
//
#include <hip/hip_runtime.h>
#include <stdint.h>

// FP32->FP64 bit-pulse converter, round 8.
// Round-7 tile body UNCHANGED. One structural change: persistent-style
// grid-stride launch (2048 blocks = 8 blocks/CU) with manual 2-deep
// load pipelining, replacing the 65,536-block one-tile-per-wave launch.
// Rationale: kernel was at ~2.5 TB/s (not BW-bound, not VALU-bound) --
// wave turnover + single-load-in-flight starved the memory system.
//
// Wave tile = 8 rows (1024 B in / 2048 B out).
//  Load:  lane k loads float4 #k (coalesced, nontemporal).
//  Pack:  4 ballots -> 256 tile bits in wave-uniform 64-bit masks.
//  Convert: lane k rebuilds row lane/8's word, integer FP32->FP64 bits.
//  Shuffle: two 64-bit ds_bpermute redistributions so each store
//           instruction writes a contiguous aligned 1024-B span.

typedef float fvec4 __attribute__((ext_vector_type(4)));

__device__ __forceinline__ uint32_t spread4(uint32_t x) {
    // spread low 8 bits: bit i -> bit 4*i
    x &= 0xffu;
    x = (x | (x << 12)) & 0x000F000Fu;
    x = (x | (x << 6))  & 0x03030303u;
    x = (x | (x << 3))  & 0x11111111u;
    return x;
}

__device__ __forceinline__ uint64_t shfl64(uint64_t x, int srcLane) {
    int addr = srcLane << 2;  // ds_bpermute index is lane*4 bytes
    uint32_t lo = (uint32_t)__builtin_amdgcn_ds_bpermute(addr, (int)(uint32_t)x);
    uint32_t hi = (uint32_t)__builtin_amdgcn_ds_bpermute(addr, (int)(uint32_t)(x >> 32));
    return ((uint64_t)hi << 32) | lo;
}

__device__ __forceinline__ fvec4 nib2f(uint32_t nib) {
    fvec4 f;
    f.x = (nib & 1u) ? 1.0f : 0.0f;
    f.y = (nib & 2u) ? 1.0f : 0.0f;
    f.z = (nib & 4u) ? 1.0f : 0.0f;
    f.w = (nib & 8u) ? 1.0f : 0.0f;
    return f;
}

__device__ __forceinline__ void process_tile(fvec4 g, int lane, fvec4* __restrict__ ob) {
    // ---- pack all 256 tile bits: bit k of bc = (elem 4k+c of tile) != 0 ----
    uint64_t b0 = __ballot(g.x != 0.0f);
    uint64_t b1 = __ballot(g.y != 0.0f);
    uint64_t b2 = __ballot(g.z != 0.0f);
    uint64_t b3 = __ballot(g.w != 0.0f);

    // ---- rebuild this lane's row word (row = lane/8, MSB-first) ----
    int sh = lane & 56;  // 8 * (lane/8)
    uint32_t u = spread4((uint32_t)(b0 >> sh))
               | (spread4((uint32_t)(b1 >> sh)) << 1)
               | (spread4((uint32_t)(b2 >> sh)) << 2)
               | (spread4((uint32_t)(b3 >> sh)) << 3);

    // ---- FP32 -> FP64 bit conversion (once per lane) ----
    uint32_t v = __brev(u);              // standard IEEE FP32 word
    uint32_t E = (v >> 23) & 0xffu;
    uint32_t M = v & 0x7fffffu;
    uint64_t S = (uint64_t)(v >> 31);
    uint64_t E64 = E ? (uint64_t)(E + 896u) : 0ull;  // rebias 1023-127
    uint64_t M64 = (uint64_t)M << 29;
    if (E == 255u) {                     // Inf / NaN
        E64 = 2047ull;
        M64 = M ? (1ull << 51) : 0ull;   // quiet NaN: mantissa MSB only
    }
    uint64_t v64 = (S << 63) | (E64 << 52) | M64;
    uint64_t rr  = __brevll(v64);        // bit j == output element j of row

    // ---- redistribute rows so each store is a contiguous 1024-B span ----
    int src0 = (lane & 48) >> 1;         // 8 * (lane/16): holder of row lane/16
    uint64_t r0 = shfl64(rr, src0);      // row lane/16      (chunks 0..63)
    uint64_t r1 = shfl64(rr, src0 + 32); // row 4 + lane/16  (chunks 64..127)

    int nsh = (lane & 15) * 4;           // my nibble within the row
    fvec4 f0 = nib2f((uint32_t)(r0 >> nsh) & 0xfu);
    fvec4 f1 = nib2f((uint32_t)(r1 >> nsh) & 0xfu);

    __builtin_nontemporal_store(f0, ob);       // chunks 0..63
    __builtin_nontemporal_store(f1, ob + 64);  // chunks 64..127
}

__global__ __launch_bounds__(256, 8) void
fp32_to_fp64_pulse_kernel(const fvec4* __restrict__ in,
                          fvec4* __restrict__ out, int nwaves) {
    const int lane  = threadIdx.x & 63;
    const int wid0  = (int)((blockIdx.x * blockDim.x + threadIdx.x) >> 6);
    const int wstep = (int)((gridDim.x * blockDim.x) >> 6);

    // Grid-stride over tiles, 2-deep: two NT loads in flight per wave.
    // w / nwaves / wstep are wave-uniform -> ballots stay convergent.
    int w = wid0;
    for (; w + wstep < nwaves; w += 2 * wstep) {
        fvec4 g0 = __builtin_nontemporal_load(in + (size_t)w * 64 + lane);
        fvec4 g1 = __builtin_nontemporal_load(in + (size_t)(w + wstep) * 64 + lane);
        process_tile(g0, lane, out + (size_t)w * 128 + lane);
        process_tile(g1, lane, out + (size_t)(w + wstep) * 128 + lane);
    }
    if (w < nwaves) {
        fvec4 g = __builtin_nontemporal_load(in + (size_t)w * 64 + lane);
        process_tile(g, lane, out + (size_t)w * 128 + lane);
    }
}

extern "C" void kernel_launch(void* const* d_in, const int* in_sizes, int n_in,
                              void* d_out, int out_size, void* d_ws, size_t ws_size,
                              hipStream_t stream) {
    (void)n_in; (void)d_ws; (void)ws_size; (void)out_size;
    const fvec4* in = (const fvec4*)d_in[0];
    fvec4* out = (fvec4*)d_out;
    int nrows  = in_sizes[0] / 32;       // B = 2097152
    int nwaves = nrows / 8;              // 8 rows per wave
    const int block = 256;
    // 8 blocks/CU x 256 CU = 2048 persistent blocks (32 waves/CU), grid-stride.
    int needed = (nwaves * 64 + block - 1) / block;
    int grid   = needed < 2048 ? needed : 2048;
    fp32_to_fp64_pulse_kernel<<<grid, block, 0, stream>>>(in, out, nwaves);
}

// Round 2
// 668.729 us; speedup vs baseline: 1.0174x; 1.0174x over previous
//
#include <hip/hip_runtime.h>
#include <stdint.h>

// FP32->FP64 bit-pulse converter, round 9.
// Round-7 tile body UNCHANGED, round-7 non-persistent geometry restored.
// One structural change: 4 tiles per wave, ALL FOUR nontemporal loads
// issued up-front, then process+store each tile in turn.
// Rationale: r7/r8 kept <=1 load in flight per wave (load -> vmcnt drain
// for ballot -> long serial chain -> store -> retire), so the chip
// alternated load/compute/store phases in lockstep at ~2.4 TB/s.
// Batched load-ahead keeps 3 loads in flight under each tile's compute
// (first ballot waits only vmcnt(3)), 4x per-wave MLP, 3.4x wave-slot
// efficiency.
//
// Wave tile = 8 rows (1024 B in / 2048 B out).
//  Load:  lane k loads float4 #k (coalesced, nontemporal).
//  Pack:  4 ballots -> 256 tile bits in wave-uniform 64-bit masks.
//  Convert: lane k rebuilds row lane/8's word, integer FP32->FP64 bits.
//  Shuffle: two 64-bit ds_bpermute redistributions so each store
//           instruction writes a contiguous aligned 1024-B span.

typedef float fvec4 __attribute__((ext_vector_type(4)));

__device__ __forceinline__ uint32_t spread4(uint32_t x) {
    // spread low 8 bits: bit i -> bit 4*i
    x &= 0xffu;
    x = (x | (x << 12)) & 0x000F000Fu;
    x = (x | (x << 6))  & 0x03030303u;
    x = (x | (x << 3))  & 0x11111111u;
    return x;
}

__device__ __forceinline__ uint64_t shfl64(uint64_t x, int srcLane) {
    int addr = srcLane << 2;  // ds_bpermute index is lane*4 bytes
    uint32_t lo = (uint32_t)__builtin_amdgcn_ds_bpermute(addr, (int)(uint32_t)x);
    uint32_t hi = (uint32_t)__builtin_amdgcn_ds_bpermute(addr, (int)(uint32_t)(x >> 32));
    return ((uint64_t)hi << 32) | lo;
}

__device__ __forceinline__ fvec4 nib2f(uint32_t nib) {
    fvec4 f;
    f.x = (nib & 1u) ? 1.0f : 0.0f;
    f.y = (nib & 2u) ? 1.0f : 0.0f;
    f.z = (nib & 4u) ? 1.0f : 0.0f;
    f.w = (nib & 8u) ? 1.0f : 0.0f;
    return f;
}

__device__ __forceinline__ void process_tile(fvec4 g, int lane, fvec4* __restrict__ ob) {
    // ---- pack all 256 tile bits: bit k of bc = (elem 4k+c of tile) != 0 ----
    uint64_t b0 = __ballot(g.x != 0.0f);
    uint64_t b1 = __ballot(g.y != 0.0f);
    uint64_t b2 = __ballot(g.z != 0.0f);
    uint64_t b3 = __ballot(g.w != 0.0f);

    // ---- rebuild this lane's row word (row = lane/8, MSB-first) ----
    int sh = lane & 56;  // 8 * (lane/8)
    uint32_t u = spread4((uint32_t)(b0 >> sh))
               | (spread4((uint32_t)(b1 >> sh)) << 1)
               | (spread4((uint32_t)(b2 >> sh)) << 2)
               | (spread4((uint32_t)(b3 >> sh)) << 3);

    // ---- FP32 -> FP64 bit conversion (once per lane) ----
    uint32_t v = __brev(u);              // standard IEEE FP32 word
    uint32_t E = (v >> 23) & 0xffu;
    uint32_t M = v & 0x7fffffu;
    uint64_t S = (uint64_t)(v >> 31);
    uint64_t E64 = E ? (uint64_t)(E + 896u) : 0ull;  // rebias 1023-127
    uint64_t M64 = (uint64_t)M << 29;
    if (E == 255u) {                     // Inf / NaN
        E64 = 2047ull;
        M64 = M ? (1ull << 51) : 0ull;   // quiet NaN: mantissa MSB only
    }
    uint64_t v64 = (S << 63) | (E64 << 52) | M64;
    uint64_t rr  = __brevll(v64);        // bit j == output element j of row

    // ---- redistribute rows so each store is a contiguous 1024-B span ----
    int src0 = (lane & 48) >> 1;         // 8 * (lane/16): holder of row lane/16
    uint64_t r0 = shfl64(rr, src0);      // row lane/16      (chunks 0..63)
    uint64_t r1 = shfl64(rr, src0 + 32); // row 4 + lane/16  (chunks 64..127)

    int nsh = (lane & 15) * 4;           // my nibble within the row
    fvec4 f0 = nib2f((uint32_t)(r0 >> nsh) & 0xfu);
    fvec4 f1 = nib2f((uint32_t)(r1 >> nsh) & 0xfu);

    __builtin_nontemporal_store(f0, ob);       // chunks 0..63
    __builtin_nontemporal_store(f1, ob + 64);  // chunks 64..127
}

__global__ __launch_bounds__(256) void
fp32_to_fp64_pulse_kernel(const fvec4* __restrict__ in,
                          fvec4* __restrict__ out) {
    int lane = threadIdx.x & 63;
    int wv   = (int)((blockIdx.x * blockDim.x + threadIdx.x) >> 6);
    size_t t0 = (size_t)wv * 4;          // 4 consecutive tiles per wave

    // ---- all 4 tile loads issued up-front: 3 stay in flight under compute ----
    const fvec4* ib = in + t0 * 64 + lane;
    fvec4 g0 = __builtin_nontemporal_load(ib);
    fvec4 g1 = __builtin_nontemporal_load(ib + 64);
    fvec4 g2 = __builtin_nontemporal_load(ib + 128);
    fvec4 g3 = __builtin_nontemporal_load(ib + 192);

    fvec4* ob = out + t0 * 128 + lane;
    process_tile(g0, lane, ob);
    process_tile(g1, lane, ob + 128);
    process_tile(g2, lane, ob + 256);
    process_tile(g3, lane, ob + 384);
}

extern "C" void kernel_launch(void* const* d_in, const int* in_sizes, int n_in,
                              void* d_out, int out_size, void* d_ws, size_t ws_size,
                              hipStream_t stream) {
    (void)n_in; (void)d_ws; (void)ws_size; (void)out_size;
    const fvec4* in = (const fvec4*)d_in[0];
    fvec4* out = (fvec4*)d_out;
    int nrows  = in_sizes[0] / 32;       // B = 2097152
    int ntiles = nrows / 8;              // 8 rows per tile
    int nwaves = ntiles / 4;             // 4 tiles per wave (exact: B % 256 == 0)
    int threads = nwaves * 64;
    const int block = 256;
    int grid = threads / block;          // exact
    fp32_to_fp64_pulse_kernel<<<grid, block, 0, stream>>>(in, out);
}

// Round 3
// 668.595 us; speedup vs baseline: 1.0176x; 1.0002x over previous
//
#include <hip/hip_runtime.h>
#include <stdint.h>

// FP32->FP64 bit-pulse converter, round 10.
// Round-7 tile body UNCHANGED, round-7 non-persistent geometry.
// Two changes vs r7, zero changes vs its inner math:
//   1. __launch_bounds__(256, 8): pin VGPR <= 64 so occupancy is the
//      full 32 waves/CU (r7/r9 left the register allocator unbounded --
//      the only un-refuted World-A limiter).
//   2. 2 tiles per wave, both NT loads issued up-front (2x per-wave MLP,
//      +8 VGPRs of staging -- fits the 64-VGPR cap without spill,
//      unlike r8's grid-stride variant).
// r8 (persistent 2-deep) and r9 (4-deep unbounded) both regressed;
// this is the remaining untried cell: occupancy-pinned, non-persistent,
// modest load-ahead.
//
// Wave tile = 8 rows (1024 B in / 2048 B out).
//  Load:  lane k loads float4 #k (coalesced, nontemporal).
//  Pack:  4 ballots -> 256 tile bits in wave-uniform 64-bit masks.
//  Convert: lane k rebuilds row lane/8's word, integer FP32->FP64 bits.
//  Shuffle: two 64-bit ds_bpermute redistributions so each store
//           instruction writes a contiguous aligned 1024-B span.

typedef float fvec4 __attribute__((ext_vector_type(4)));

__device__ __forceinline__ uint32_t spread4(uint32_t x) {
    // spread low 8 bits: bit i -> bit 4*i
    x &= 0xffu;
    x = (x | (x << 12)) & 0x000F000Fu;
    x = (x | (x << 6))  & 0x03030303u;
    x = (x | (x << 3))  & 0x11111111u;
    return x;
}

__device__ __forceinline__ uint64_t shfl64(uint64_t x, int srcLane) {
    int addr = srcLane << 2;  // ds_bpermute index is lane*4 bytes
    uint32_t lo = (uint32_t)__builtin_amdgcn_ds_bpermute(addr, (int)(uint32_t)x);
    uint32_t hi = (uint32_t)__builtin_amdgcn_ds_bpermute(addr, (int)(uint32_t)(x >> 32));
    return ((uint64_t)hi << 32) | lo;
}

__device__ __forceinline__ fvec4 nib2f(uint32_t nib) {
    fvec4 f;
    f.x = (nib & 1u) ? 1.0f : 0.0f;
    f.y = (nib & 2u) ? 1.0f : 0.0f;
    f.z = (nib & 4u) ? 1.0f : 0.0f;
    f.w = (nib & 8u) ? 1.0f : 0.0f;
    return f;
}

__device__ __forceinline__ void process_tile(fvec4 g, int lane, fvec4* __restrict__ ob) {
    // ---- pack all 256 tile bits: bit k of bc = (elem 4k+c of tile) != 0 ----
    uint64_t b0 = __ballot(g.x != 0.0f);
    uint64_t b1 = __ballot(g.y != 0.0f);
    uint64_t b2 = __ballot(g.z != 0.0f);
    uint64_t b3 = __ballot(g.w != 0.0f);

    // ---- rebuild this lane's row word (row = lane/8, MSB-first) ----
    int sh = lane & 56;  // 8 * (lane/8)
    uint32_t u = spread4((uint32_t)(b0 >> sh))
               | (spread4((uint32_t)(b1 >> sh)) << 1)
               | (spread4((uint32_t)(b2 >> sh)) << 2)
               | (spread4((uint32_t)(b3 >> sh)) << 3);

    // ---- FP32 -> FP64 bit conversion (once per lane) ----
    uint32_t v = __brev(u);              // standard IEEE FP32 word
    uint32_t E = (v >> 23) & 0xffu;
    uint32_t M = v & 0x7fffffu;
    uint64_t S = (uint64_t)(v >> 31);
    uint64_t E64 = E ? (uint64_t)(E + 896u) : 0ull;  // rebias 1023-127
    uint64_t M64 = (uint64_t)M << 29;
    if (E == 255u) {                     // Inf / NaN
        E64 = 2047ull;
        M64 = M ? (1ull << 51) : 0ull;   // quiet NaN: mantissa MSB only
    }
    uint64_t v64 = (S << 63) | (E64 << 52) | M64;
    uint64_t rr  = __brevll(v64);        // bit j == output element j of row

    // ---- redistribute rows so each store is a contiguous 1024-B span ----
    int src0 = (lane & 48) >> 1;         // 8 * (lane/16): holder of row lane/16
    uint64_t r0 = shfl64(rr, src0);      // row lane/16      (chunks 0..63)
    uint64_t r1 = shfl64(rr, src0 + 32); // row 4 + lane/16  (chunks 64..127)

    int nsh = (lane & 15) * 4;           // my nibble within the row
    fvec4 f0 = nib2f((uint32_t)(r0 >> nsh) & 0xfu);
    fvec4 f1 = nib2f((uint32_t)(r1 >> nsh) & 0xfu);

    __builtin_nontemporal_store(f0, ob);       // chunks 0..63
    __builtin_nontemporal_store(f1, ob + 64);  // chunks 64..127
}

__global__ __launch_bounds__(256, 8) void
fp32_to_fp64_pulse_kernel(const fvec4* __restrict__ in,
                          fvec4* __restrict__ out) {
    int lane = threadIdx.x & 63;
    int wv   = (int)((blockIdx.x * blockDim.x + threadIdx.x) >> 6);
    size_t t0 = (size_t)wv * 2;          // 2 consecutive tiles per wave

    // ---- both tile loads issued up-front: 1 stays in flight under compute ----
    const fvec4* ib = in + t0 * 64 + lane;
    fvec4 g0 = __builtin_nontemporal_load(ib);
    fvec4 g1 = __builtin_nontemporal_load(ib + 64);

    fvec4* ob = out + t0 * 128 + lane;
    process_tile(g0, lane, ob);
    process_tile(g1, lane, ob + 128);
}

extern "C" void kernel_launch(void* const* d_in, const int* in_sizes, int n_in,
                              void* d_out, int out_size, void* d_ws, size_t ws_size,
                              hipStream_t stream) {
    (void)n_in; (void)d_ws; (void)ws_size; (void)out_size;
    const fvec4* in = (const fvec4*)d_in[0];
    fvec4* out = (fvec4*)d_out;
    int nrows  = in_sizes[0] / 32;       // B = 2097152
    int ntiles = nrows / 8;              // 8 rows per tile
    int nwaves = ntiles / 2;             // 2 tiles per wave (exact: B % 128 == 0)
    int threads = nwaves * 64;
    const int block = 256;
    int grid = threads / block;          // exact
    fp32_to_fp64_pulse_kernel<<<grid, block, 0, stream>>>(in, out);
}

// Round 4
// 657.295 us; speedup vs baseline: 1.0351x; 1.0172x over previous
//
#include <hip/hip_runtime.h>
#include <stdint.h>

// FP32->FP64 bit-pulse converter, round 11 == round 7 VERBATIM (session best,
// 656.7 us). Rounds 8/9/10 (persistent 2-deep, 4-deep batch, occupancy-pinned
// 2-deep) all regressed 12-24 us: per-wave work increases only add overhead.
// Conclusion: timed region = ~343 us poison-fill + restore overhead + a kernel
// near the 768-MiB mixed-stream roofline. Restoring the measured optimum.
//
// Wave tile = 8 rows (1024 B in / 2048 B out), 1 tile per wave.
//  Load:  lane k loads float4 #k (coalesced, nontemporal).
//  Pack:  4 ballots -> 256 tile bits in wave-uniform 64-bit masks.
//  Convert: lane k rebuilds row lane/8's word, integer FP32->FP64 bits.
//  Shuffle: two 64-bit ds_bpermute redistributions so each store
//           instruction writes a contiguous aligned 1024-B span.

typedef float fvec4 __attribute__((ext_vector_type(4)));

__device__ __forceinline__ uint32_t spread4(uint32_t x) {
    // spread low 8 bits: bit i -> bit 4*i
    x &= 0xffu;
    x = (x | (x << 12)) & 0x000F000Fu;
    x = (x | (x << 6))  & 0x03030303u;
    x = (x | (x << 3))  & 0x11111111u;
    return x;
}

__device__ __forceinline__ uint64_t shfl64(uint64_t x, int srcLane) {
    int addr = srcLane << 2;  // ds_bpermute index is lane*4 bytes
    uint32_t lo = (uint32_t)__builtin_amdgcn_ds_bpermute(addr, (int)(uint32_t)x);
    uint32_t hi = (uint32_t)__builtin_amdgcn_ds_bpermute(addr, (int)(uint32_t)(x >> 32));
    return ((uint64_t)hi << 32) | lo;
}

__device__ __forceinline__ fvec4 nib2f(uint32_t nib) {
    fvec4 f;
    f.x = (nib & 1u) ? 1.0f : 0.0f;
    f.y = (nib & 2u) ? 1.0f : 0.0f;
    f.z = (nib & 4u) ? 1.0f : 0.0f;
    f.w = (nib & 8u) ? 1.0f : 0.0f;
    return f;
}

__global__ __launch_bounds__(256) void
fp32_to_fp64_pulse_kernel(const fvec4* __restrict__ in,
                          fvec4* __restrict__ out) {
    int lane = threadIdx.x & 63;
    int w = (int)((blockIdx.x * blockDim.x + threadIdx.x) >> 6);

    // ---- coalesced load: 8 rows = 64 float4 (nontemporal, read-once) ----
    fvec4 g = __builtin_nontemporal_load(in + (size_t)w * 64 + lane);

    // ---- pack all 256 tile bits: bit k of bc = (elem 4k+c of tile) != 0 ----
    uint64_t b0 = __ballot(g.x != 0.0f);
    uint64_t b1 = __ballot(g.y != 0.0f);
    uint64_t b2 = __ballot(g.z != 0.0f);
    uint64_t b3 = __ballot(g.w != 0.0f);

    // ---- rebuild this lane's row word (row = lane/8, MSB-first) ----
    int sh = lane & 56;  // 8 * (lane/8)
    uint32_t u = spread4((uint32_t)(b0 >> sh))
               | (spread4((uint32_t)(b1 >> sh)) << 1)
               | (spread4((uint32_t)(b2 >> sh)) << 2)
               | (spread4((uint32_t)(b3 >> sh)) << 3);

    // ---- FP32 -> FP64 bit conversion (once per lane) ----
    uint32_t v = __brev(u);              // standard IEEE FP32 word
    uint32_t E = (v >> 23) & 0xffu;
    uint32_t M = v & 0x7fffffu;
    uint64_t S = (uint64_t)(v >> 31);
    uint64_t E64 = E ? (uint64_t)(E + 896u) : 0ull;  // rebias 1023-127
    uint64_t M64 = (uint64_t)M << 29;
    if (E == 255u) {                     // Inf / NaN
        E64 = 2047ull;
        M64 = M ? (1ull << 51) : 0ull;   // quiet NaN: mantissa MSB only
    }
    uint64_t v64 = (S << 63) | (E64 << 52) | M64;
    uint64_t rr  = __brevll(v64);        // bit j == output element j of row

    // ---- redistribute rows so each store is a contiguous 1024-B span ----
    int src0 = (lane & 48) >> 1;         // 8 * (lane/16): holder of row lane/16
    uint64_t r0 = shfl64(rr, src0);      // row lane/16      (chunks 0..63)
    uint64_t r1 = shfl64(rr, src0 + 32); // row 4 + lane/16  (chunks 64..127)

    int nsh = (lane & 15) * 4;           // my nibble within the row
    fvec4 f0 = nib2f((uint32_t)(r0 >> nsh) & 0xfu);
    fvec4 f1 = nib2f((uint32_t)(r1 >> nsh) & 0xfu);

    fvec4* ob = out + (size_t)w * 128 + lane;
    __builtin_nontemporal_store(f0, ob);       // chunks 0..63
    __builtin_nontemporal_store(f1, ob + 64);  // chunks 64..127
}

extern "C" void kernel_launch(void* const* d_in, const int* in_sizes, int n_in,
                              void* d_out, int out_size, void* d_ws, size_t ws_size,
                              hipStream_t stream) {
    (void)n_in; (void)d_ws; (void)ws_size; (void)out_size;
    const fvec4* in = (const fvec4*)d_in[0];
    fvec4* out = (fvec4*)d_out;
    int nrows  = in_sizes[0] / 32;       // B = 2097152
    int nwaves = nrows / 8;              // 8 rows per wave
    int threads = nwaves * 64;
    const int block = 256;
    int grid = threads / block;          // exact: B divisible by 32
    fp32_to_fp64_pulse_kernel<<<grid, block, 0, stream>>>(in, out);
}